// Round 12
// baseline (380.767 us; speedup 1.0000x reference)
//
#include <hip/hip_runtime.h>
#include <hip/hip_cooperative_groups.h>
#include <cstddef>
#include <cstdint>

namespace cg = cooperative_groups;

#define D_MODEL 1024
#define D_STATE 16
#define D_INNER 2048
#define BATCH 2
#define SEQ 4096
#define NTOK (BATCH * SEQ)
#define EPS_LN 1e-5f

// ws float offsets
#define WS_PA 0          // [16][1024] PA'' = norm_w ⊙ (W_in^T A)
#define WS_PB 16384      // [16][1024] PB'' = norm_w ⊙ (W_in^T B)
#define WS_M 32768       // [16][1024] M^T, M = W_out @ C
#define WS_CA 49152      // [16] bias-only part of c'A
#define WS_CB 49168      // [16]
#define WS_TP 49184      // [2 mat][16 n][4 dq] T partials (128)
#define WS_UP 49312      // [2 mat][16 n][4 dq] U partials (128)
#define WS_A 49440               // [32 seq][4096] decay gates (transposed)
#define WS_U (WS_A + NTOK * 16)  // [32 seq][4096] input drive (transposed)
#define WS_S (WS_U + NTOK * 16)  // [32 seq][4096] states (transposed)
#define WS_PPA (WS_S + NTOK * 16)     // [64 ec][16 n][1024 d] partials (4MB)
#define WS_PPB (WS_PPA + 64 * 16384)  // [64 ec][16 n][1024 d] (4MB)
#define WS_PM (WS_PPB + 64 * 16384)   // [16 ec][16 n][1024 d] (1MB)

// ===========================================================================
// Shared phase bodies (used by both the mega kernel and the fallback chain).
// ===========================================================================
__device__ __forceinline__ void phaseW_unit(
    int u, int tid, int lane, int wv, float4* smem4,
    const float* __restrict__ W_in, const float* __restrict__ W_out,
    const float* __restrict__ C, const float* __restrict__ A,
    const float* __restrict__ Bs, const float* __restrict__ b_in,
    float* __restrict__ ws) {
  if (u < 1024) {
    float4* lds4 = smem4;
    const int mat = u >> 9;
    const int bb = u & 511;
    const int dg = bb >> 6;
    const int ec = bb & 63;
    const int dl = tid & 31;
    const int eo = tid >> 5;

    const float4* __restrict__ W4 = reinterpret_cast<const float4*>(W_in);
    const float4* __restrict__ P4 =
        reinterpret_cast<const float4*>(mat == 0 ? A : Bs);

    float4 acc[16];
#pragma unroll
    for (int n = 0; n < 16; ++n) acc[n] = make_float4(0.f, 0.f, 0.f, 0.f);

#pragma unroll
    for (int k = 0; k < 4; ++k) {
      const int e = ec * 32 + eo * 4 + k;
      const float4 w4 = W4[(size_t)e * 256 + dg * 32 + dl];
      float4 pe[4];
#pragma unroll
      for (int q = 0; q < 4; ++q) pe[q] = P4[(size_t)e * 4 + q];
#pragma unroll
      for (int q = 0; q < 4; ++q) {
        const float p0 = pe[q].x, p1 = pe[q].y, p2 = pe[q].z, p3 = pe[q].w;
        acc[q * 4 + 0].x = fmaf(w4.x, p0, acc[q * 4 + 0].x);
        acc[q * 4 + 0].y = fmaf(w4.y, p0, acc[q * 4 + 0].y);
        acc[q * 4 + 0].z = fmaf(w4.z, p0, acc[q * 4 + 0].z);
        acc[q * 4 + 0].w = fmaf(w4.w, p0, acc[q * 4 + 0].w);
        acc[q * 4 + 1].x = fmaf(w4.x, p1, acc[q * 4 + 1].x);
        acc[q * 4 + 1].y = fmaf(w4.y, p1, acc[q * 4 + 1].y);
        acc[q * 4 + 1].z = fmaf(w4.z, p1, acc[q * 4 + 1].z);
        acc[q * 4 + 1].w = fmaf(w4.w, p1, acc[q * 4 + 1].w);
        acc[q * 4 + 2].x = fmaf(w4.x, p2, acc[q * 4 + 2].x);
        acc[q * 4 + 2].y = fmaf(w4.y, p2, acc[q * 4 + 2].y);
        acc[q * 4 + 2].z = fmaf(w4.z, p2, acc[q * 4 + 2].z);
        acc[q * 4 + 2].w = fmaf(w4.w, p2, acc[q * 4 + 2].w);
        acc[q * 4 + 3].x = fmaf(w4.x, p3, acc[q * 4 + 3].x);
        acc[q * 4 + 3].y = fmaf(w4.y, p3, acc[q * 4 + 3].y);
        acc[q * 4 + 3].z = fmaf(w4.z, p3, acc[q * 4 + 3].z);
        acc[q * 4 + 3].w = fmaf(w4.w, p3, acc[q * 4 + 3].w);
      }
    }
#pragma unroll
    for (int n = 0; n < 16; ++n) {
      acc[n].x += __shfl_xor(acc[n].x, 32);
      acc[n].y += __shfl_xor(acc[n].y, 32);
      acc[n].z += __shfl_xor(acc[n].z, 32);
      acc[n].w += __shfl_xor(acc[n].w, 32);
    }
    if (wv >= 1 && lane < 32) {
#pragma unroll
      for (int n = 0; n < 16; ++n)
        lds4[(wv - 1) * 512 + n * 32 + lane] = acc[n];
    }
    __syncthreads();
    if (wv == 0 && lane < 32) {
      float4* pp4 =
          reinterpret_cast<float4*>(ws + (mat == 0 ? WS_PPA : WS_PPB));
#pragma unroll
      for (int n = 0; n < 16; ++n) {
        const float4 a0 = lds4[n * 32 + lane];
        const float4 a1 = lds4[512 + n * 32 + lane];
        const float4 a2 = lds4[1024 + n * 32 + lane];
        float4 r = acc[n];
        r.x += a0.x + a1.x + a2.x;
        r.y += a0.y + a1.y + a2.y;
        r.z += a0.z + a1.z + a2.z;
        r.w += a0.w + a1.w + a2.w;
        pp4[(size_t)(ec * 16 + n) * 256 + dg * 32 + lane] = r;
      }
    }
  } else if (u < 3072) {
    float* ct = reinterpret_cast<float*>(smem4);  // [16][132]
    const int mb = u - 1024;
    const int dg = mb >> 4;
    const int ec = mb & 15;
    const int td = tid >> 5;
    const int te = tid & 31;
    const int e0 = ec * 128;
    const float4* __restrict__ W4 = reinterpret_cast<const float4*>(W_out);
    const float4* __restrict__ C4 = reinterpret_cast<const float4*>(C);
#pragma unroll
    for (int r = 0; r < 2; ++r) {
      const int idx = r * 256 + tid;
      const int el = idx >> 2;
      const int q = idx & 3;
      const float4 cv = C4[(size_t)(e0 + el) * 4 + q];
      ct[(q * 4 + 0) * 132 + el] = cv.x;
      ct[(q * 4 + 1) * 132 + el] = cv.y;
      ct[(q * 4 + 2) * 132 + el] = cv.z;
      ct[(q * 4 + 3) * 132 + el] = cv.w;
    }
    __syncthreads();
    const int d = dg * 8 + td;
    const float4 w4 = W4[(size_t)d * 512 + ec * 32 + te];
    const float4* __restrict__ ct4 = reinterpret_cast<const float4*>(ct);
    float acc[16];
#pragma unroll
    for (int n = 0; n < 16; ++n) {
      const float4 cv = ct4[n * 33 + te];
      acc[n] = w4.x * cv.x + w4.y * cv.y + w4.z * cv.z + w4.w * cv.w;
    }
#pragma unroll
    for (int off = 1; off < 32; off <<= 1) {
#pragma unroll
      for (int n = 0; n < 16; ++n) acc[n] += __shfl_xor(acc[n], off);
    }
    if (te == 0) {
      float* pm = ws + WS_PM;
#pragma unroll
      for (int n = 0; n < 16; ++n)
        pm[(size_t)(ec * 16 + n) * 1024 + d] = acc[n];
    }
  } else {
    float* red = reinterpret_cast<float*>(smem4);
    const int which = u - 3072;
    const float* __restrict__ P = (which == 0) ? A : Bs;
    float acc[16];
#pragma unroll
    for (int n = 0; n < 16; ++n) acc[n] = 0.f;
    for (int e = tid; e < D_INNER; e += 256) {
      const float w = b_in[e];
      const float* pe = P + (size_t)e * 16;
#pragma unroll
      for (int n = 0; n < 16; ++n) acc[n] = fmaf(w, pe[n], acc[n]);
    }
#pragma unroll
    for (int n = 0; n < 16; ++n) {
#pragma unroll
      for (int off = 32; off; off >>= 1) acc[n] += __shfl_xor(acc[n], off);
    }
    if (lane == 0) {
#pragma unroll
      for (int n = 0; n < 16; ++n) red[wv * 16 + n] = acc[n];
    }
    __syncthreads();
    if (tid < 16) {
      ws[WS_CA + which * 16 + tid] =
          red[tid] + red[16 + tid] + red[32 + tid] + red[48 + tid];
    }
  }
}

__device__ __forceinline__ void phaseR_unit(int u, int tid, float4* smem4,
                                            const float* __restrict__ nw,
                                            const float* __restrict__ nb,
                                            float* __restrict__ ws) {
  float4* red4 = smem4;
  const int grp = u >> 6;  // 0:PA 1:PB 2:M
  const int sub = u & 63;
  const int n = sub >> 2;
  const int dq = sub & 3;
  const int dl = tid & 63;
  const int cg_ = tid >> 6;
  const float4* __restrict__ pp4 = reinterpret_cast<const float4*>(
      ws + (grp == 0 ? WS_PPA : (grp == 1 ? WS_PPB : WS_PM)));
  const int base = n * 256 + dq * 64 + dl;

  float4 acc = make_float4(0.f, 0.f, 0.f, 0.f);
  if (grp < 2) {
#pragma unroll
    for (int j = 0; j < 16; ++j) {
      const float4 v = pp4[(size_t)(cg_ * 16 + j) * 4096 + base];
      acc.x += v.x;
      acc.y += v.y;
      acc.z += v.z;
      acc.w += v.w;
    }
  } else {
#pragma unroll
    for (int j = 0; j < 4; ++j) {
      const float4 v = pp4[(size_t)(cg_ * 4 + j) * 4096 + base];
      acc.x += v.x;
      acc.y += v.y;
      acc.z += v.z;
      acc.w += v.w;
    }
  }
  red4[cg_ * 64 + dl] = acc;
  __syncthreads();
  if (tid < 64) {
    const float4 a1 = red4[64 + dl];
    const float4 a2 = red4[128 + dl];
    const float4 a3 = red4[192 + dl];
    float4 r = red4[dl];
    r.x += a1.x + a2.x + a3.x;
    r.y += a1.y + a2.y + a3.y;
    r.z += a1.z + a2.z + a3.z;
    r.w += a1.w + a2.w + a3.w;
    if (grp == 2) {
      reinterpret_cast<float4*>(ws + WS_M)[n * 256 + dq * 64 + dl] = r;
    } else {
      const float4 w4 = reinterpret_cast<const float4*>(nw)[dq * 64 + dl];
      const float4 b4 = reinterpret_cast<const float4*>(nb)[dq * 64 + dl];
      float4 vf;
      vf.x = r.x * w4.x;
      vf.y = r.y * w4.y;
      vf.z = r.z * w4.z;
      vf.w = r.w * w4.w;
      reinterpret_cast<float4*>(ws + (grp == 0 ? WS_PA : WS_PB))
          [n * 256 + dq * 64 + dl] = vf;
      float tP = vf.x + vf.y + vf.z + vf.w;
      float uP = b4.x * r.x + b4.y * r.y + b4.z * r.z + b4.w * r.w;
#pragma unroll
      for (int off = 32; off; off >>= 1) {
        tP += __shfl_xor(tP, off);
        uP += __shfl_xor(uP, off);
      }
      if (dl == 0) {
        ws[WS_TP + grp * 64 + n * 4 + dq] = tP;
        ws[WS_UP + grp * 64 + n * 4 + dq] = uP;
      }
    }
  }
}

// Token unit: 8 tokens (2 per wave). Needs TA/TB/cA/cB preloaded.
__device__ __forceinline__ void phaseT_unit(
    int u, int tid, int lane, int wv, float4* smem4,
    const float* __restrict__ x, const float* __restrict__ ws, float TA,
    float TB, float cA, float cB, float* __restrict__ a_t,
    float* __restrict__ u_t) {
  float4* lds4 = smem4;  // [32*69]
  const int g = lane >> 4;
  const int np = lane & 15;
  const int t0 = u * 8 + wv * 2;
  const float4* __restrict__ x4 = reinterpret_cast<const float4*>(x);
  const float4* __restrict__ ws4 = reinterpret_cast<const float4*>(ws);

  float sum[2], sq[2], SA[2], SB[2];
#pragma unroll
  for (int t = 0; t < 2; ++t) {
    sum[t] = 0.f;
    sq[t] = 0.f;
    SA[t] = 0.f;
    SB[t] = 0.f;
  }

  for (int p = 0; p < 4; ++p) {
    __syncthreads();
#pragma unroll
    for (int i = 0; i < 8; ++i) {
      const int idx = i * 256 + tid;
      const int r = idx >> 6;
      const int uu = idx & 63;
      lds4[r * 69 + uu + (uu >> 4)] = ws4[(size_t)r * 256 + p * 64 + uu];
    }
    __syncthreads();
#pragma unroll
    for (int t = 0; t < 2; ++t) {
      const float4 xs = x4[(size_t)(t0 + t) * 256 + p * 64 + lane];
      sum[t] += xs.x + xs.y + xs.z + xs.w;
      sq[t] = fmaf(xs.x, xs.x, sq[t]);
      sq[t] = fmaf(xs.y, xs.y, sq[t]);
      sq[t] = fmaf(xs.z, xs.z, sq[t]);
      sq[t] = fmaf(xs.w, xs.w, sq[t]);
    }
#pragma unroll
    for (int j = 0; j < 16; ++j) {
      const float4 pa = lds4[np * 69 + g * 17 + j];
      const float4 pb = lds4[(16 + np) * 69 + g * 17 + j];
#pragma unroll
      for (int t = 0; t < 2; ++t) {
        const float4 xb = x4[(size_t)(t0 + t) * 256 + p * 64 + g * 16 + j];
        SA[t] = fmaf(xb.x, pa.x, SA[t]);
        SA[t] = fmaf(xb.y, pa.y, SA[t]);
        SA[t] = fmaf(xb.z, pa.z, SA[t]);
        SA[t] = fmaf(xb.w, pa.w, SA[t]);
        SB[t] = fmaf(xb.x, pb.x, SB[t]);
        SB[t] = fmaf(xb.y, pb.y, SB[t]);
        SB[t] = fmaf(xb.z, pb.z, SB[t]);
        SB[t] = fmaf(xb.w, pb.w, SB[t]);
      }
    }
  }
#pragma unroll
  for (int t = 0; t < 2; ++t) {
    float s = sum[t], q = sq[t];
#pragma unroll
    for (int off = 32; off; off >>= 1) {
      s += __shfl_xor(s, off);
      q += __shfl_xor(q, off);
    }
    const float mu = s * (1.0f / 1024.0f);
    const float var = fmaf(-mu, mu, q * (1.0f / 1024.0f));
    const float rstd = rsqrtf(var + EPS_LN);
    float sa = SA[t] + __shfl_xor(SA[t], 16);
    sa += __shfl_xor(sa, 32);
    float sb = SB[t] + __shfl_xor(SB[t], 16);
    sb += __shfl_xor(sb, 32);
    if (g == 0) {
      const float zA = fmaf(rstd, fmaf(-mu, TA, sa), cA);
      const float zB = fmaf(rstd, fmaf(-mu, TB, sb), cB);
      const int tok = t0 + t;
      const int bb = tok >> 12;
      const int ss = tok & 4095;
      const size_t row = (size_t)(bb * 16 + np) * 4096 + ss;
      a_t[row] = 1.0f / (1.0f + __expf(-zA));
      u_t[row] = zB;
    }
  }
}

__device__ __forceinline__ void phaseS_unit(int seq, int tid, int lane, int wv,
                                            float4* smem4,
                                            const float* __restrict__ a_t,
                                            const float* __restrict__ u_t,
                                            float* __restrict__ st_t) {
  const size_t rowbase = (size_t)seq * 4096;
  const float4* __restrict__ a4 =
      reinterpret_cast<const float4*>(a_t + rowbase) + tid * 4;
  const float4* __restrict__ u4 =
      reinterpret_cast<const float4*>(u_t + rowbase) + tid * 4;

  float4 av[4], uv[4];
#pragma unroll
  for (int q = 0; q < 4; ++q) {
    av[q] = a4[q];
    uv[q] = u4[q];
  }
  float Ag = 1.f, Ug = 0.f;
#pragma unroll
  for (int q = 0; q < 4; ++q) {
    Ug = fmaf(Ug, av[q].x, uv[q].x);
    Ag *= av[q].x;
    Ug = fmaf(Ug, av[q].y, uv[q].y);
    Ag *= av[q].y;
    Ug = fmaf(Ug, av[q].z, uv[q].z);
    Ag *= av[q].z;
    Ug = fmaf(Ug, av[q].w, uv[q].w);
    Ag *= av[q].w;
  }
#pragma unroll
  for (int off = 1; off < 64; off <<= 1) {
    const float Ap = __shfl_up(Ag, off);
    const float Up = __shfl_up(Ug, off);
    if (lane >= off) {
      Ug = fmaf(Up, Ag, Ug);
      Ag = Ap * Ag;
    }
  }
  float* sA = reinterpret_cast<float*>(smem4);
  float* sU = sA + 4;
  if (lane == 63) {
    sA[wv] = Ag;
    sU[wv] = Ug;
  }
  __syncthreads();
  float c = 0.f;
  for (int w = 0; w < wv; ++w) c = fmaf(c, sA[w], sU[w]);
  const float Ae = __shfl_up(Ag, 1);
  const float Ue = __shfl_up(Ug, 1);
  const float carry = (lane == 0) ? c : fmaf(c, Ae, Ue);
  float s = carry;
  float4* __restrict__ st4 =
      reinterpret_cast<float4*>(st_t + rowbase) + tid * 4;
#pragma unroll
  for (int q = 0; q < 4; ++q) {
    float4 ov;
    s = fmaf(s, av[q].x, uv[q].x);
    ov.x = s;
    s = fmaf(s, av[q].y, uv[q].y);
    ov.y = s;
    s = fmaf(s, av[q].z, uv[q].z);
    ov.z = s;
    s = fmaf(s, av[q].w, uv[q].w);
    ov.w = s;
    st4[q] = ov;
  }
}

__device__ __forceinline__ void phaseO_unit(int u, int lane, int wv,
                                            const float* __restrict__ x,
                                            const float* __restrict__ ws,
                                            const float* __restrict__ b_out,
                                            float* __restrict__ out) {
  const int t0 = u * 8 + wv * 2;
  const int bb = t0 >> 12;
  const int s0 = t0 & 4095;
  const float4* __restrict__ x4 = reinterpret_cast<const float4*>(x);
  const float4* __restrict__ M4 = reinterpret_cast<const float4*>(ws + WS_M);
  const float4* __restrict__ b4 = reinterpret_cast<const float4*>(b_out);
  const float* __restrict__ st = ws + WS_S;
  float4* __restrict__ o4 = reinterpret_cast<float4*>(out);

  float s[2][16];
#pragma unroll
  for (int n = 0; n < 16; ++n) {
    const float* row = st + (size_t)(bb * 16 + n) * 4096 + s0;
#pragma unroll
    for (int tt = 0; tt < 2; ++tt) s[tt][n] = row[tt];
  }
#pragma unroll
  for (int k = 0; k < 4; ++k) {
    const float4 bv = b4[k * 64 + lane];
    float4 acc[2];
#pragma unroll
    for (int tt = 0; tt < 2; ++tt) {
      const float4 xv = x4[(size_t)(t0 + tt) * 256 + k * 64 + lane];
      acc[tt] =
          make_float4(xv.x + bv.x, xv.y + bv.y, xv.z + bv.z, xv.w + bv.w);
    }
#pragma unroll
    for (int n = 0; n < 16; ++n) {
      const float4 m = M4[(size_t)n * 256 + k * 64 + lane];
#pragma unroll
      for (int tt = 0; tt < 2; ++tt) {
        acc[tt].x = fmaf(s[tt][n], m.x, acc[tt].x);
        acc[tt].y = fmaf(s[tt][n], m.y, acc[tt].y);
        acc[tt].z = fmaf(s[tt][n], m.z, acc[tt].z);
        acc[tt].w = fmaf(s[tt][n], m.w, acc[tt].w);
      }
    }
#pragma unroll
    for (int tt = 0; tt < 2; ++tt)
      o4[(size_t)(t0 + tt) * 256 + k * 64 + lane] = acc[tt];
  }
}

// ===========================================================================
// Cooperative mega kernel — every phase grid-strided (works at any grid size)
// ===========================================================================
__global__ __launch_bounds__(256, 4) void mega_kernel(
    const float* __restrict__ x, const float* __restrict__ nw,
    const float* __restrict__ nb, const float* __restrict__ W_in,
    const float* __restrict__ b_in, const float* __restrict__ A,
    const float* __restrict__ Bs, const float* __restrict__ C,
    const float* __restrict__ W_out, const float* __restrict__ b_out,
    float* __restrict__ ws, float* __restrict__ out) {
  cg::grid_group grid = cg::this_grid();
  __shared__ float4 smem4[2208];  // 35328 B union
  const int bid = blockIdx.x;
  const int tid = threadIdx.x;
  const int lane = tid & 63;
  const int wv = tid >> 6;
  const int nblk = gridDim.x;

  for (int u = bid; u < 3074; u += nblk) {
    __syncthreads();
    phaseW_unit(u, tid, lane, wv, smem4, W_in, W_out, C, A, Bs, b_in, ws);
  }
  grid.sync();

  for (int u = bid; u < 192; u += nblk) {
    __syncthreads();
    phaseR_unit(u, tid, smem4, nw, nb, ws);
  }
  grid.sync();

  {
    const int np = lane & 15;
    const float* tp = ws + WS_TP;
    const float* up = ws + WS_UP;
    const float TA =
        tp[np * 4] + tp[np * 4 + 1] + tp[np * 4 + 2] + tp[np * 4 + 3];
    const float TB = tp[64 + np * 4] + tp[64 + np * 4 + 1] +
                     tp[64 + np * 4 + 2] + tp[64 + np * 4 + 3];
    const float cA = ws[WS_CA + np] + up[np * 4] + up[np * 4 + 1] +
                     up[np * 4 + 2] + up[np * 4 + 3];
    const float cB = ws[WS_CB + np] + up[64 + np * 4] + up[64 + np * 4 + 1] +
                     up[64 + np * 4 + 2] + up[64 + np * 4 + 3];
    for (int u = bid; u < NTOK / 8; u += nblk)
      phaseT_unit(u, tid, lane, wv, smem4, x, ws, TA, TB, cA, cB, ws + WS_A,
                  ws + WS_U);
  }
  grid.sync();

  for (int u = bid; u < 32; u += nblk) {
    __syncthreads();
    phaseS_unit(u, tid, lane, wv, smem4, ws + WS_A, ws + WS_U, ws + WS_S);
  }
  grid.sync();

  for (int u = bid; u < NTOK / 8; u += nblk)
    phaseO_unit(u, lane, wv, x, ws, b_out, out);
}

// ===========================================================================
// Fallback chain (r10 structure) — used if cooperative launch is unsupported
// ===========================================================================
__global__ __launch_bounds__(256) void fb_weights(
    const float* __restrict__ W_in, const float* __restrict__ W_out,
    const float* __restrict__ C, const float* __restrict__ A,
    const float* __restrict__ Bs, const float* __restrict__ b_in,
    float* __restrict__ ws) {
  __shared__ float4 smem4[1536];
  const int tid = threadIdx.x;
  phaseW_unit(blockIdx.x, tid, tid & 63, tid >> 6, smem4, W_in, W_out, C, A,
              Bs, b_in, ws);
}

__global__ __launch_bounds__(256) void fb_reduce(const float* __restrict__ nw,
                                                 const float* __restrict__ nb,
                                                 float* __restrict__ ws) {
  __shared__ float4 red4[256];
  phaseR_unit(blockIdx.x, threadIdx.x, red4, nw, nb, ws);
}

__global__ __launch_bounds__(256) void fb_token(const float* __restrict__ x,
                                                const float* __restrict__ ws,
                                                float* __restrict__ a_t,
                                                float* __restrict__ u_t) {
  __shared__ float4 lds4[2208];
  const int tid = threadIdx.x;
  const int lane = tid & 63;
  const int np = lane & 15;
  const float* tp = ws + WS_TP;
  const float* up = ws + WS_UP;
  const float TA =
      tp[np * 4] + tp[np * 4 + 1] + tp[np * 4 + 2] + tp[np * 4 + 3];
  const float TB = tp[64 + np * 4] + tp[64 + np * 4 + 1] +
                   tp[64 + np * 4 + 2] + tp[64 + np * 4 + 3];
  const float cA = ws[WS_CA + np] + up[np * 4] + up[np * 4 + 1] +
                   up[np * 4 + 2] + up[np * 4 + 3];
  const float cB = ws[WS_CB + np] + up[64 + np * 4] + up[64 + np * 4 + 1] +
                   up[64 + np * 4 + 2] + up[64 + np * 4 + 3];
  // 2 units of 8 tokens per block = 16 tokens (r10 config)
  phaseT_unit(blockIdx.x * 2, tid, lane, tid >> 6, lds4, x, ws, TA, TB, cA, cB,
              a_t, u_t);
  phaseT_unit(blockIdx.x * 2 + 1, tid, lane, tid >> 6, lds4, x, ws, TA, TB, cA,
              cB, a_t, u_t);
}

__global__ __launch_bounds__(256) void fb_scan(const float* __restrict__ a_t,
                                               const float* __restrict__ u_t,
                                               float* __restrict__ st_t) {
  __shared__ float4 smem4[4];
  const int tid = threadIdx.x;
  phaseS_unit(blockIdx.x, tid, tid & 63, tid >> 6, smem4, a_t, u_t, st_t);
}

__global__ __launch_bounds__(256) void fb_out(const float* __restrict__ x,
                                              const float* __restrict__ ws,
                                              const float* __restrict__ b_out,
                                              float* __restrict__ out) {
  const int tid = threadIdx.x;
  phaseO_unit(blockIdx.x, tid & 63, tid >> 6, x, ws, b_out, out);
}

// ---------------------------------------------------------------------------
extern "C" void kernel_launch(void* const* d_in, const int* in_sizes, int n_in,
                              void* d_out, int out_size, void* d_ws,
                              size_t ws_size, hipStream_t stream) {
  const float* x = (const float*)d_in[0];
  const float* norm_w = (const float*)d_in[1];
  const float* norm_b = (const float*)d_in[2];
  const float* W_in = (const float*)d_in[3];
  const float* b_in = (const float*)d_in[4];
  const float* A = (const float*)d_in[5];
  const float* B_ssm = (const float*)d_in[6];
  const float* C_ssm = (const float*)d_in[7];
  const float* W_out = (const float*)d_in[8];
  const float* b_out = (const float*)d_in[9];
  float* ws = (float*)d_ws;
  float* out = (float*)d_out;

  // Capture-safe, deterministic capability probing.
  int dev = 0;
  hipGetDevice(&dev);
  int coopSupported = 0;
  hipDeviceGetAttribute(&coopSupported, hipDeviceAttributeCooperativeLaunch,
                        dev);
  int cus = 256;
  hipDeviceGetAttribute(&cus, hipDeviceAttributeMultiprocessorCount, dev);
  int maxPerCU = 0;
  if (hipOccupancyMaxActiveBlocksPerMultiprocessor(
          &maxPerCU, (const void*)mega_kernel, 256, 0) != hipSuccess)
    maxPerCU = 0;

  if (coopSupported && maxPerCU >= 1) {
    long cap = (long)maxPerCU * (long)cus;
    int nblk = (int)(cap < 768 ? cap : 768);  // stay below exact-fit
    void* args[] = {&x,     &norm_w, &norm_b, &W_in,  &b_in, &A,
                    &B_ssm, &C_ssm,  &W_out,  &b_out, &ws,   &out};
    hipLaunchCooperativeKernel((const void*)mega_kernel, dim3(nblk), dim3(256),
                               args, 0, stream);
  } else {
    fb_weights<<<3074, 256, 0, stream>>>(W_in, W_out, C_ssm, A, B_ssm, b_in,
                                         ws);
    fb_reduce<<<192, 256, 0, stream>>>(norm_w, norm_b, ws);
    fb_token<<<512, 256, 0, stream>>>(x, ws, ws + WS_A, ws + WS_U);
    fb_scan<<<32, 256, 0, stream>>>(ws + WS_A, ws + WS_U, ws + WS_S);
    fb_out<<<1024, 256, 0, stream>>>(x, ws, b_out, out);
  }
}

// Round 13
// 68.425 us; speedup vs baseline: 5.5647x; 5.5647x over previous
//
#include <hip/hip_runtime.h>
#include <cstddef>
#include <cstdint>

#define D_MODEL 1024
#define D_STATE 16
#define D_INNER 2048
#define BATCH 2
#define SEQ 4096
#define NTOK (BATCH * SEQ)
#define EPS_LN 1e-5f

// ws float offsets
#define WS_PA 0          // [16][1024] PA'' = norm_w ⊙ (W_in^T A)
#define WS_PB 16384      // [16][1024] PB'' = norm_w ⊙ (W_in^T B)
#define WS_M 32768       // [16][1024] M^T, M = W_out @ C
#define WS_CA 49152      // [16] bias-only part of c'A
#define WS_CB 49168      // [16]
#define WS_TP 49184      // [2 mat][16 n][4 dq] T partials (128)
#define WS_UP 49312      // [2 mat][16 n][4 dq] U partials (128)
#define WS_A 49440               // [32 seq][4096] decay gates (transposed)
#define WS_U (WS_A + NTOK * 16)  // [32 seq][4096] input drive (transposed)
#define WS_S (WS_U + NTOK * 16)  // [32 seq][4096] states (transposed)
#define WS_PPA (WS_S + NTOK * 16)     // [16 ec][16 n][1024 d] partials (1MB)
#define WS_PPB (WS_PPA + 16 * 16384)  // [16 ec][16 n][1024 d] (1MB)
#define WS_PM (WS_PPB + 16 * 16384)   // [16 ec][16 n][1024 d] (1MB)

// ---------------------------------------------------------------------------
// K1: fused weights kernel. 2562 blocks:
//   bid < 512         : PA/PB partials (256 A + 256 B); block = (dg 16 x 64d,
//                       ec 16 x 128e); thread = (dl 16 f4-d, eo 16 x 8e).
//                       Wave-load of W_in row-slice = 4x256B segments.
//                       16 partial chunks (was 64) -> reduce reads 4x less.
//   512 <= bid < 2560 : M^T partials (dg 128 x ec 16), C staged transposed.
//   bid 2560/2561     : bias cA/cB.
// ---------------------------------------------------------------------------
__global__ __launch_bounds__(256) void weights_kernel(
    const float* __restrict__ W_in, const float* __restrict__ W_out,
    const float* __restrict__ C, const float* __restrict__ A,
    const float* __restrict__ Bs, const float* __restrict__ b_in,
    float* __restrict__ ws) {
  __shared__ float4 smem4[1536];  // 24 KB union
  const int bid = blockIdx.x;
  const int tid = threadIdx.x;
  const int lane = tid & 63;
  const int wv = tid >> 6;

  if (bid < 512) {
    // ---- PA/PB partials
    float4* lds4 = smem4;
    const int mat = bid >> 8;  // 0: A, 1: B
    const int bb = bid & 255;
    const int dg = bb >> 4;   // 0..15 -> d-range 64
    const int ec = bb & 15;   // 0..15 -> e-range 128
    const int dl = tid & 15;  // f4 index within 16
    const int eo = tid >> 4;  // 0..15 (8 e each)

    const float4* __restrict__ W4 = reinterpret_cast<const float4*>(W_in);
    const float4* __restrict__ P4 =
        reinterpret_cast<const float4*>(mat == 0 ? A : Bs);

    float4 acc[16];
#pragma unroll
    for (int n = 0; n < 16; ++n) acc[n] = make_float4(0.f, 0.f, 0.f, 0.f);

#pragma unroll
    for (int k = 0; k < 8; ++k) {
      const int e = ec * 128 + eo * 8 + k;
      const float4 w4 = W4[(size_t)e * 256 + dg * 16 + dl];
      float4 pe[4];
#pragma unroll
      for (int q = 0; q < 4; ++q) pe[q] = P4[(size_t)e * 4 + q];
#pragma unroll
      for (int q = 0; q < 4; ++q) {
        const float p0 = pe[q].x, p1 = pe[q].y, p2 = pe[q].z, p3 = pe[q].w;
        acc[q * 4 + 0].x = fmaf(w4.x, p0, acc[q * 4 + 0].x);
        acc[q * 4 + 0].y = fmaf(w4.y, p0, acc[q * 4 + 0].y);
        acc[q * 4 + 0].z = fmaf(w4.z, p0, acc[q * 4 + 0].z);
        acc[q * 4 + 0].w = fmaf(w4.w, p0, acc[q * 4 + 0].w);
        acc[q * 4 + 1].x = fmaf(w4.x, p1, acc[q * 4 + 1].x);
        acc[q * 4 + 1].y = fmaf(w4.y, p1, acc[q * 4 + 1].y);
        acc[q * 4 + 1].z = fmaf(w4.z, p1, acc[q * 4 + 1].z);
        acc[q * 4 + 1].w = fmaf(w4.w, p1, acc[q * 4 + 1].w);
        acc[q * 4 + 2].x = fmaf(w4.x, p2, acc[q * 4 + 2].x);
        acc[q * 4 + 2].y = fmaf(w4.y, p2, acc[q * 4 + 2].y);
        acc[q * 4 + 2].z = fmaf(w4.z, p2, acc[q * 4 + 2].z);
        acc[q * 4 + 2].w = fmaf(w4.w, p2, acc[q * 4 + 2].w);
        acc[q * 4 + 3].x = fmaf(w4.x, p3, acc[q * 4 + 3].x);
        acc[q * 4 + 3].y = fmaf(w4.y, p3, acc[q * 4 + 3].y);
        acc[q * 4 + 3].z = fmaf(w4.z, p3, acc[q * 4 + 3].z);
        acc[q * 4 + 3].w = fmaf(w4.w, p3, acc[q * 4 + 3].w);
      }
    }
    // fold the 4 eo-sub-groups within the wave (lane bits 4,5)
#pragma unroll
    for (int n = 0; n < 16; ++n) {
      acc[n].x += __shfl_xor(acc[n].x, 16);
      acc[n].y += __shfl_xor(acc[n].y, 16);
      acc[n].z += __shfl_xor(acc[n].z, 16);
      acc[n].w += __shfl_xor(acc[n].w, 16);
      acc[n].x += __shfl_xor(acc[n].x, 32);
      acc[n].y += __shfl_xor(acc[n].y, 32);
      acc[n].z += __shfl_xor(acc[n].z, 32);
      acc[n].w += __shfl_xor(acc[n].w, 32);
    }
    if (wv >= 1 && lane < 16) {
#pragma unroll
      for (int n = 0; n < 16; ++n)
        lds4[(wv - 1) * 256 + n * 16 + lane] = acc[n];
    }
    __syncthreads();
    if (wv == 0 && lane < 16) {
      float4* pp4 =
          reinterpret_cast<float4*>(ws + (mat == 0 ? WS_PPA : WS_PPB));
#pragma unroll
      for (int n = 0; n < 16; ++n) {
        const float4 a0 = lds4[n * 16 + lane];
        const float4 a1 = lds4[256 + n * 16 + lane];
        const float4 a2 = lds4[512 + n * 16 + lane];
        float4 r = acc[n];
        r.x += a0.x + a1.x + a2.x;
        r.y += a0.y + a1.y + a2.y;
        r.z += a0.z + a1.z + a2.z;
        r.w += a0.w + a1.w + a2.w;
        pp4[(size_t)(ec * 16 + n) * 256 + dg * 16 + lane] = r;
      }
    }
  } else if (bid < 2560) {
    // ---- M^T partials
    float* ct = reinterpret_cast<float*>(smem4);  // [16][132]
    const int mb = bid - 512;
    const int dg = mb >> 4;   // 0..127 -> 8 d's
    const int ec = mb & 15;   // 0..15 -> 128 e's
    const int td = tid >> 5;  // 0..7
    const int te = tid & 31;  // 0..31 f4 of e
    const int e0 = ec * 128;
    const float4* __restrict__ W4 = reinterpret_cast<const float4*>(W_out);
    const float4* __restrict__ C4 = reinterpret_cast<const float4*>(C);
#pragma unroll
    for (int r = 0; r < 2; ++r) {
      const int idx = r * 256 + tid;  // 0..511
      const int el = idx >> 2;
      const int q = idx & 3;
      const float4 cv = C4[(size_t)(e0 + el) * 4 + q];
      ct[(q * 4 + 0) * 132 + el] = cv.x;
      ct[(q * 4 + 1) * 132 + el] = cv.y;
      ct[(q * 4 + 2) * 132 + el] = cv.z;
      ct[(q * 4 + 3) * 132 + el] = cv.w;
    }
    __syncthreads();
    const int d = dg * 8 + td;
    const float4 w4 = W4[(size_t)d * 512 + ec * 32 + te];
    const float4* __restrict__ ct4 = reinterpret_cast<const float4*>(ct);
    float acc[16];
#pragma unroll
    for (int n = 0; n < 16; ++n) {
      const float4 cv = ct4[n * 33 + te];
      acc[n] = w4.x * cv.x + w4.y * cv.y + w4.z * cv.z + w4.w * cv.w;
    }
#pragma unroll
    for (int off = 1; off < 32; off <<= 1) {
#pragma unroll
      for (int n = 0; n < 16; ++n) acc[n] += __shfl_xor(acc[n], off);
    }
    if (te == 0) {
      float* pm = ws + WS_PM;
#pragma unroll
      for (int n = 0; n < 16; ++n)
        pm[(size_t)(ec * 16 + n) * 1024 + d] = acc[n];
    }
  } else {
    // ---- bias: cA (bid 2560), cB (bid 2561)
    float* red = reinterpret_cast<float*>(smem4);
    const int which = bid - 2560;
    const float* __restrict__ P = (which == 0) ? A : Bs;
    float acc[16];
#pragma unroll
    for (int n = 0; n < 16; ++n) acc[n] = 0.f;
    for (int e = tid; e < D_INNER; e += 256) {
      const float w = b_in[e];
      const float* pe = P + (size_t)e * 16;
#pragma unroll
      for (int n = 0; n < 16; ++n) acc[n] = fmaf(w, pe[n], acc[n]);
    }
#pragma unroll
    for (int n = 0; n < 16; ++n) {
#pragma unroll
      for (int off = 32; off; off >>= 1) acc[n] += __shfl_xor(acc[n], off);
    }
    if (lane == 0) {
#pragma unroll
      for (int n = 0; n < 16; ++n) red[wv * 16 + n] = acc[n];
    }
    __syncthreads();
    if (tid < 16) {
      ws[WS_CA + which * 16 + tid] =
          red[tid] + red[16 + tid] + red[32 + tid] + red[48 + tid];
    }
  }
}

// ---------------------------------------------------------------------------
// K2: parallel fold of partials (16 chunks each now). 192 blocks =
// (grp 3) x (n 16) x (dq 4). 256 threads = 64 f4-lanes x 4 chunk-groups.
// ---------------------------------------------------------------------------
__global__ __launch_bounds__(256) void reduce_kernel(
    const float* __restrict__ nw, const float* __restrict__ nb,
    float* __restrict__ ws) {
  __shared__ float4 red4[256];
  const int bid = blockIdx.x;
  const int tid = threadIdx.x;
  const int grp = bid >> 6;  // 0:PA 1:PB 2:M
  const int sub = bid & 63;
  const int n = sub >> 2;
  const int dq = sub & 3;
  const int dl = tid & 63;
  const int cg = tid >> 6;
  const float4* __restrict__ pp4 = reinterpret_cast<const float4*>(
      ws + (grp == 0 ? WS_PPA : (grp == 1 ? WS_PPB : WS_PM)));
  const int base = n * 256 + dq * 64 + dl;

  float4 acc = make_float4(0.f, 0.f, 0.f, 0.f);
#pragma unroll
  for (int j = 0; j < 4; ++j) {
    const float4 v = pp4[(size_t)(cg * 4 + j) * 4096 + base];
    acc.x += v.x;
    acc.y += v.y;
    acc.z += v.z;
    acc.w += v.w;
  }
  red4[cg * 64 + dl] = acc;
  __syncthreads();
  if (tid < 64) {
    const float4 a1 = red4[64 + dl];
    const float4 a2 = red4[128 + dl];
    const float4 a3 = red4[192 + dl];
    float4 r = red4[dl];
    r.x += a1.x + a2.x + a3.x;
    r.y += a1.y + a2.y + a3.y;
    r.z += a1.z + a2.z + a3.z;
    r.w += a1.w + a2.w + a3.w;
    if (grp == 2) {
      reinterpret_cast<float4*>(ws + WS_M)[n * 256 + dq * 64 + dl] = r;
    } else {
      const float4 w4 = reinterpret_cast<const float4*>(nw)[dq * 64 + dl];
      const float4 b4 = reinterpret_cast<const float4*>(nb)[dq * 64 + dl];
      float4 vf;
      vf.x = r.x * w4.x;
      vf.y = r.y * w4.y;
      vf.z = r.z * w4.z;
      vf.w = r.w * w4.w;
      reinterpret_cast<float4*>(ws + (grp == 0 ? WS_PA : WS_PB))
          [n * 256 + dq * 64 + dl] = vf;
      float tP = vf.x + vf.y + vf.z + vf.w;
      float uP = b4.x * r.x + b4.y * r.y + b4.z * r.z + b4.w * r.w;
#pragma unroll
      for (int off = 32; off; off >>= 1) {
        tP += __shfl_xor(tP, off);
        uP += __shfl_xor(uP, off);
      }
      if (dl == 0) {
        ws[WS_TP + grp * 64 + n * 4 + dq] = tP;
        ws[WS_UP + grp * 64 + n * 4 + dq] = uP;
      }
    }
  }
}

// ---------------------------------------------------------------------------
// K3: token kernel. 512 blocks x 16 tokens (4 tok/wave -> 2 waves/SIMD).
// Writes a,u TRANSPOSED: a_t[(b*16+n)*4096 + s].
// ---------------------------------------------------------------------------
__global__ __launch_bounds__(256) void token_kernel(
    const float* __restrict__ x, const float* __restrict__ ws,
    float* __restrict__ a_t, float* __restrict__ u_t) {
  __shared__ float4 lds4[32 * 69];
  const int tid = threadIdx.x;
  const int lane = tid & 63;
  const int wv = tid >> 6;
  const int g = lane >> 4;
  const int np = lane & 15;
  const int t0 = blockIdx.x * 16 + wv * 4;

  const float4* __restrict__ x4 = reinterpret_cast<const float4*>(x);
  const float4* __restrict__ ws4 = reinterpret_cast<const float4*>(ws);

  const float* tp = ws + WS_TP;
  const float* up = ws + WS_UP;
  const float TA =
      tp[np * 4] + tp[np * 4 + 1] + tp[np * 4 + 2] + tp[np * 4 + 3];
  const float TB = tp[64 + np * 4] + tp[64 + np * 4 + 1] +
                   tp[64 + np * 4 + 2] + tp[64 + np * 4 + 3];
  const float cA = ws[WS_CA + np] + up[np * 4] + up[np * 4 + 1] +
                   up[np * 4 + 2] + up[np * 4 + 3];
  const float cB = ws[WS_CB + np] + up[64 + np * 4] + up[64 + np * 4 + 1] +
                   up[64 + np * 4 + 2] + up[64 + np * 4 + 3];

  float sum[4], sq[4], SA[4], SB[4];
#pragma unroll
  for (int t = 0; t < 4; ++t) {
    sum[t] = 0.f;
    sq[t] = 0.f;
    SA[t] = 0.f;
    SB[t] = 0.f;
  }

  for (int p = 0; p < 4; ++p) {
    __syncthreads();
#pragma unroll
    for (int i = 0; i < 8; ++i) {
      const int idx = i * 256 + tid;
      const int r = idx >> 6;
      const int u = idx & 63;
      lds4[r * 69 + u + (u >> 4)] = ws4[(size_t)r * 256 + p * 64 + u];
    }
    __syncthreads();
#pragma unroll
    for (int t = 0; t < 4; ++t) {
      const float4 xs = x4[(size_t)(t0 + t) * 256 + p * 64 + lane];
      sum[t] += xs.x + xs.y + xs.z + xs.w;
      sq[t] = fmaf(xs.x, xs.x, sq[t]);
      sq[t] = fmaf(xs.y, xs.y, sq[t]);
      sq[t] = fmaf(xs.z, xs.z, sq[t]);
      sq[t] = fmaf(xs.w, xs.w, sq[t]);
    }
#pragma unroll
    for (int j = 0; j < 16; ++j) {
      const float4 pa = lds4[np * 69 + g * 17 + j];
      const float4 pb = lds4[(16 + np) * 69 + g * 17 + j];
#pragma unroll
      for (int t = 0; t < 4; ++t) {
        const float4 xb = x4[(size_t)(t0 + t) * 256 + p * 64 + g * 16 + j];
        SA[t] = fmaf(xb.x, pa.x, SA[t]);
        SA[t] = fmaf(xb.y, pa.y, SA[t]);
        SA[t] = fmaf(xb.z, pa.z, SA[t]);
        SA[t] = fmaf(xb.w, pa.w, SA[t]);
        SB[t] = fmaf(xb.x, pb.x, SB[t]);
        SB[t] = fmaf(xb.y, pb.y, SB[t]);
        SB[t] = fmaf(xb.z, pb.z, SB[t]);
        SB[t] = fmaf(xb.w, pb.w, SB[t]);
      }
    }
  }
#pragma unroll
  for (int t = 0; t < 4; ++t) {
    float s = sum[t], q = sq[t];
#pragma unroll
    for (int off = 32; off; off >>= 1) {
      s += __shfl_xor(s, off);
      q += __shfl_xor(q, off);
    }
    const float mu = s * (1.0f / 1024.0f);
    const float var = fmaf(-mu, mu, q * (1.0f / 1024.0f));
    const float rstd = rsqrtf(var + EPS_LN);
    float sa = SA[t] + __shfl_xor(SA[t], 16);
    sa += __shfl_xor(sa, 32);
    float sb = SB[t] + __shfl_xor(SB[t], 16);
    sb += __shfl_xor(sb, 32);
    if (g == 0) {
      const float zA = fmaf(rstd, fmaf(-mu, TA, sa), cA);
      const float zB = fmaf(rstd, fmaf(-mu, TB, sb), cB);
      const int tok = t0 + t;
      const int bb = tok >> 12;
      const int ss = tok & 4095;
      const size_t row = (size_t)(bb * 16 + np) * 4096 + ss;
      a_t[row] = 1.0f / (1.0f + __expf(-zA));
      u_t[row] = zB;
    }
  }
}

// ---------------------------------------------------------------------------
// K4: single-kernel scan. One block per sequence (32 blocks, 256 threads).
// ---------------------------------------------------------------------------
__global__ __launch_bounds__(256) void scan_kernel(
    const float* __restrict__ a_t, const float* __restrict__ u_t,
    float* __restrict__ st_t) {
  const int seq = blockIdx.x;
  const int tid = threadIdx.x;
  const int lane = tid & 63;
  const int wv = tid >> 6;
  const size_t rowbase = (size_t)seq * 4096;
  const float4* __restrict__ a4 =
      reinterpret_cast<const float4*>(a_t + rowbase) + tid * 4;
  const float4* __restrict__ u4 =
      reinterpret_cast<const float4*>(u_t + rowbase) + tid * 4;

  float4 av[4], uv[4];
#pragma unroll
  for (int q = 0; q < 4; ++q) {
    av[q] = a4[q];
    uv[q] = u4[q];
  }
  float Ag = 1.f, Ug = 0.f;
#pragma unroll
  for (int q = 0; q < 4; ++q) {
    Ug = fmaf(Ug, av[q].x, uv[q].x);
    Ag *= av[q].x;
    Ug = fmaf(Ug, av[q].y, uv[q].y);
    Ag *= av[q].y;
    Ug = fmaf(Ug, av[q].z, uv[q].z);
    Ag *= av[q].z;
    Ug = fmaf(Ug, av[q].w, uv[q].w);
    Ag *= av[q].w;
  }
#pragma unroll
  for (int off = 1; off < 64; off <<= 1) {
    const float Ap = __shfl_up(Ag, off);
    const float Up = __shfl_up(Ug, off);
    if (lane >= off) {
      Ug = fmaf(Up, Ag, Ug);
      Ag = Ap * Ag;
    }
  }
  __shared__ float sA[4], sU[4];
  if (lane == 63) {
    sA[wv] = Ag;
    sU[wv] = Ug;
  }
  __syncthreads();
  float c = 0.f;
  for (int w = 0; w < wv; ++w) c = fmaf(c, sA[w], sU[w]);
  const float Ae = __shfl_up(Ag, 1);
  const float Ue = __shfl_up(Ug, 1);
  const float carry = (lane == 0) ? c : fmaf(c, Ae, Ue);
  float s = carry;
  float4* __restrict__ st4 =
      reinterpret_cast<float4*>(st_t + rowbase) + tid * 4;
#pragma unroll
  for (int q = 0; q < 4; ++q) {
    float4 ov;
    s = fmaf(s, av[q].x, uv[q].x);
    ov.x = s;
    s = fmaf(s, av[q].y, uv[q].y);
    ov.y = s;
    s = fmaf(s, av[q].z, uv[q].z);
    ov.z = s;
    s = fmaf(s, av[q].w, uv[q].w);
    ov.w = s;
    st4[q] = ov;
  }
}

// ---------------------------------------------------------------------------
// K5: out = states @ M^T + b_out + x. 1024 blocks x 8 tokens (2 tok/wave
// -> 4 waves/SIMD).
// ---------------------------------------------------------------------------
__global__ __launch_bounds__(256) void out_kernel(
    const float* __restrict__ x, const float* __restrict__ ws,
    const float* __restrict__ b_out, float* __restrict__ out) {
  const int tid = threadIdx.x;
  const int lane = tid & 63;
  const int wv = tid >> 6;
  const int t0 = blockIdx.x * 8 + wv * 2;
  const int bb = t0 >> 12;
  const int s0 = t0 & 4095;
  const float4* __restrict__ x4 = reinterpret_cast<const float4*>(x);
  const float4* __restrict__ M4 = reinterpret_cast<const float4*>(ws + WS_M);
  const float4* __restrict__ b4 = reinterpret_cast<const float4*>(b_out);
  const float* __restrict__ st = ws + WS_S;
  float4* __restrict__ o4 = reinterpret_cast<float4*>(out);

  float s[2][16];
#pragma unroll
  for (int n = 0; n < 16; ++n) {
    const float* row = st + (size_t)(bb * 16 + n) * 4096 + s0;
#pragma unroll
    for (int tt = 0; tt < 2; ++tt) s[tt][n] = row[tt];
  }

#pragma unroll
  for (int k = 0; k < 4; ++k) {
    const float4 bv = b4[k * 64 + lane];
    float4 acc[2];
#pragma unroll
    for (int tt = 0; tt < 2; ++tt) {
      const float4 xv = x4[(size_t)(t0 + tt) * 256 + k * 64 + lane];
      acc[tt] =
          make_float4(xv.x + bv.x, xv.y + bv.y, xv.z + bv.z, xv.w + bv.w);
    }
#pragma unroll
    for (int n = 0; n < 16; ++n) {
      const float4 m = M4[(size_t)n * 256 + k * 64 + lane];
#pragma unroll
      for (int tt = 0; tt < 2; ++tt) {
        acc[tt].x = fmaf(s[tt][n], m.x, acc[tt].x);
        acc[tt].y = fmaf(s[tt][n], m.y, acc[tt].y);
        acc[tt].z = fmaf(s[tt][n], m.z, acc[tt].z);
        acc[tt].w = fmaf(s[tt][n], m.w, acc[tt].w);
      }
    }
#pragma unroll
    for (int tt = 0; tt < 2; ++tt)
      o4[(size_t)(t0 + tt) * 256 + k * 64 + lane] = acc[tt];
  }
}

// ---------------------------------------------------------------------------
extern "C" void kernel_launch(void* const* d_in, const int* in_sizes, int n_in,
                              void* d_out, int out_size, void* d_ws,
                              size_t ws_size, hipStream_t stream) {
  const float* x = (const float*)d_in[0];
  const float* norm_w = (const float*)d_in[1];
  const float* norm_b = (const float*)d_in[2];
  const float* W_in = (const float*)d_in[3];
  const float* b_in = (const float*)d_in[4];
  const float* A = (const float*)d_in[5];
  const float* B_ssm = (const float*)d_in[6];
  const float* C_ssm = (const float*)d_in[7];
  const float* W_out = (const float*)d_in[8];
  const float* b_out = (const float*)d_in[9];
  float* ws = (float*)d_ws;
  float* out = (float*)d_out;

  weights_kernel<<<2562, 256, 0, stream>>>(W_in, W_out, C_ssm, A, B_ssm, b_in,
                                           ws);
  reduce_kernel<<<192, 256, 0, stream>>>(norm_w, norm_b, ws);
  token_kernel<<<512, 256, 0, stream>>>(x, ws, ws + WS_A, ws + WS_U);
  scan_kernel<<<32, 256, 0, stream>>>(ws + WS_A, ws + WS_U, ws + WS_S);
  out_kernel<<<1024, 256, 0, stream>>>(x, ws, b_out, out);
}